// Round 1
// baseline (243.022 us; speedup 1.0000x reference)
//
#include <hip/hip_runtime.h>
#include <hip/hip_cooperative_groups.h>
#include <cstddef>

namespace cg = cooperative_groups;

static constexpr int TT = 64;    // decoder steps
static constexpr int BB = 8;     // batch
static constexpr int SS = 512;   // source length
static constexpr int HH = 512;   // hidden

typedef __attribute__((ext_vector_type(8))) short bf16x8;
typedef __attribute__((ext_vector_type(4))) float f32x4;

__device__ __forceinline__ float fast_tanh(float x) {
  float e = __expf(2.0f * x);
  return 1.0f - 2.0f * __builtin_amdgcn_rcpf(e + 1.0f);
}
__device__ __forceinline__ unsigned short f2bf(float f) {
  unsigned u = __float_as_uint(f);
  return (unsigned short)((u + 0x7FFFu + ((u >> 16) & 1u)) >> 16);   // RNE
}

// ---------------------------------------------------------------------------
// 64x64 bf16 MFMA tile over K range; 256 sub-block threads (tid in [0,256)).
// C/D layout: col=lane&15, row=(lane>>4)*4+reg (verified in prior session).
// ---------------------------------------------------------------------------
template<int LDA, int LDB>
__device__ __forceinline__ void gemm_tile(const unsigned short* __restrict__ A,
                                          const unsigned short* __restrict__ BT,
                                          int m0, int n0, int kbeg, int kend,
                                          unsigned short (*As)[72],
                                          unsigned short (*Bs)[72],
                                          f32x4 acc[4], int tid) {
  const int w = tid >> 6, lane = tid & 63;
  const int lr = tid >> 2, lk = (tid & 3) * 16;
  const int fm = w * 16 + (lane & 15), fk = (lane >> 4) * 8;
  for (int k0 = kbeg; k0 < kend; k0 += 64) {
    const uint4* ga = (const uint4*)(A + (size_t)(m0 + lr) * LDA + k0 + lk);
    const uint4* gb = (const uint4*)(BT + (size_t)(n0 + lr) * LDB + k0 + lk);
    uint4 a0 = ga[0], a1 = ga[1], b0 = gb[0], b1 = gb[1];
    *(uint4*)&As[lr][lk] = a0;  *(uint4*)&As[lr][lk + 8] = a1;
    *(uint4*)&Bs[lr][lk] = b0;  *(uint4*)&Bs[lr][lk + 8] = b1;
    __syncthreads();
#pragma unroll
    for (int ks = 0; ks < 2; ++ks) {
      bf16x8 af = *(const bf16x8*)&As[fm][ks * 32 + fk];
#pragma unroll
      for (int j = 0; j < 4; ++j) {
        bf16x8 bf = *(const bf16x8*)&Bs[j * 16 + (lane & 15)][ks * 32 + fk];
        acc[j] = __builtin_amdgcn_mfma_f32_16x16x32_bf16(af, bf, acc[j], 0, 0, 0);
      }
    }
    __syncthreads();
  }
}

// ===========================================================================
// FUSED cooperative kernel: 256 blocks x 1024 threads, 1 block/CU.
// Partition key b = blockIdx&7 == XCD (heuristic; correctness holds even if
// the mapping differs since grid.sync provides device-scope release/acquire).
// All per-b data flows stay within one partition; weights are replicated
// per-partition so NO cross-partition data dependency exists.
// Phases: P (prep) -> G (3 GEMM jobs) -> A (scores/softmax/context) -> O (out).
// Barrier discipline: every thread of a block executes the SAME count of
// __syncthreads per phase (divergence is wave-uniform: sub = tid>>8).
// ===========================================================================
__global__ __launch_bounds__(1024)
void k_fused(const float* __restrict__ dec, const float* __restrict__ enc,
             const float* __restrict__ cov, const float* __restrict__ Wq,
             const float* __restrict__ bq, const float* __restrict__ Wc,
             const float* __restrict__ v, const float* __restrict__ Wo,
             const float* __restrict__ bo, const float* __restrict__ wcov,
             unsigned short* __restrict__ encpb, unsigned short* __restrict__ concatb,
             float* __restrict__ Ea1, unsigned short* __restrict__ Ea2b,
             unsigned short* __restrict__ wrepl,
             float* __restrict__ attn_h, float* __restrict__ align_out) {
  // 82944 B forces 1 block/CU (2x would exceed 160 KiB) -> even CU spread.
  __shared__ __align__(16) char smem[82944];
  cg::grid_group grid = cg::this_grid();

  const int blk = blockIdx.x, tid = threadIdx.x;
  const int b = blk & 7, i = blk >> 3;            // partition, index-in-partition
  unsigned short* WR = wrepl + (size_t)b * (1024u * 1024u);   // 2 MB replica
  const unsigned short* WqT = WR;
  const unsigned short* WcT = WR + 256 * 1024;
  const unsigned short* WoT = WR + 512 * 1024;    // [n][1024]

  // ---------------- Phase P: prep (b-affine) --------------------------------
  {
    // P1: encpb[b][s][:] = bf16(tanh(enc + cov*wcov)); 16 s-rows per block
    const int c = (tid & 127) * 4;
#pragma unroll
    for (int rep = 0; rep < 2; ++rep) {
      const int s = i * 16 + (tid >> 7) + rep * 8;
      const float4 ev = *(const float4*)(enc + (size_t)(s * BB + b) * HH + c);
      const float cv = cov[b * SS + s];
      const float4 wvv = *(const float4*)(wcov + c);
      ushort4 o;
      o.x = f2bf(fast_tanh(ev.x + cv * wvv.x));
      o.y = f2bf(fast_tanh(ev.y + cv * wvv.y));
      o.z = f2bf(fast_tanh(ev.z + cv * wvv.z));
      o.w = f2bf(fast_tanh(ev.w + cv * wvv.w));
      *(ushort4*)(encpb + (size_t)(b * SS + s) * HH + c) = o;
    }
    // P2: dec pack -> concatb right half; 2 t-rows per block
    if (tid < 256) {
      const int t = i * 2 + (tid >> 7);
      const int c2 = (tid & 127) * 4;
      const float4 dv = *(const float4*)(dec + (size_t)(t * BB + b) * HH + c2);
      ushort4 o;
      o.x = f2bf(dv.x); o.y = f2bf(dv.y); o.z = f2bf(dv.z); o.w = f2bf(dv.w);
      *(ushort4*)(concatb + (size_t)(b * 64 + t) * 1024 + 512 + c2) = o;
    }
    // P3: weight transposes into THIS partition's replica (8 jobs/sub-block)
    const int sub = tid >> 8, st = tid & 255;
    float (*tile)[33] = (float(*)[33])(smem + sub * 4224);
    const int r = st >> 3, c4 = (st & 7) * 4;
    for (int it = 0; it < 8; ++it) {
      int l = it * 128 + i * 4 + sub;              // [0,1024) bijective
      const float* W; unsigned short* WT; int KT;
      if (l < 256)      { W = Wq; WT = WR;              KT = 512; }
      else if (l < 512) { W = Wc; WT = WR + 256 * 1024; KT = 512;  l -= 256; }
      else              { W = Wo; WT = WR + 512 * 1024; KT = 1024; l -= 512; }
      const int n0 = (l & 15) * 32, k0 = (l >> 4) * 32;
      const float4 w4 = *(const float4*)(W + (size_t)(k0 + r) * 512 + n0 + c4);
      tile[r][c4 + 0] = w4.x; tile[r][c4 + 1] = w4.y;
      tile[r][c4 + 2] = w4.z; tile[r][c4 + 3] = w4.w;
      __syncthreads();
      unsigned short* o = WT + (size_t)(n0 + r) * KT + k0 + c4;
#pragma unroll
      for (int ii = 0; ii < 4; ++ii) o[ii] = f2bf(tile[c4 + ii][r]);
      __syncthreads();
    }
  }
  grid.sync();

  // ---------------- Phase G: a1 / a2 / attn_h-base GEMMs --------------------
  {
    const int sub = tid >> 8, st = tid & 255;
    unsigned short (*As)[72] = (unsigned short(*)[72])(smem + sub * 18432);
    unsigned short (*Bs)[72] = (unsigned short(*)[72])(smem + sub * 18432 + 9216);
    const int w4 = st >> 6, lane = st & 63;
    const int col = lane & 15, rq = lane >> 4;
    if (sub < 2) {                       // a2: Ea2b[b*512+s][n] (2 jobs/block)
      const int rem = i * 2 + sub;       // [0,64)
      const int m0 = b * 512 + (rem & 7) * 64, n0 = (rem >> 3) * 64;
      f32x4 acc[4] = {};
      gemm_tile<512, 512>(encpb, WcT, m0, n0, 0, 512, As, Bs, acc, st);
#pragma unroll
      for (int j = 0; j < 4; ++j) {
        const int n = n0 + j * 16 + col;
#pragma unroll
        for (int r = 0; r < 4; ++r) {
          const int m = m0 + w4 * 16 + rq * 4 + r;
          float val = fminf(fmaxf(acc[j][r], -10.5f), 10.5f);
          Ea2b[(size_t)m * 512 + n] = f2bf(__expf(2.0f * val));
        }
      }
    } else if (sub == 2 && i < 8) {      // a1: Ea1[b*64+t][n]
      const int m0 = b * 64, n0 = i * 64;
      f32x4 acc[4] = {};
      gemm_tile<1024, 512>(concatb + 512, WqT, m0, n0, 0, 512, As, Bs, acc, st);
#pragma unroll
      for (int j = 0; j < 4; ++j) {
        const int n = n0 + j * 16 + col;
        const float bv = bq[n];
#pragma unroll
        for (int r = 0; r < 4; ++r) {
          const int m = m0 + w4 * 16 + rq * 4 + r;
          float val = fminf(fmaxf(acc[j][r] + bv, -10.5f), 10.5f);
          Ea1[(size_t)m * 512 + n] = __expf(2.0f * val);
        }
      }
    } else if (sub == 2 && i < 16) {     // base: attn_h = dec@Wo_bot + bo
      const int m0 = b * 64, n0 = (i - 8) * 64;
      f32x4 acc[4] = {};
      gemm_tile<1024, 1024>(concatb, WoT, m0, n0, 512, 1024, As, Bs, acc, st);
#pragma unroll
      for (int j = 0; j < 4; ++j) {
        const int n = n0 + j * 16 + col;
        const float bv = bo[n];
#pragma unroll
        for (int r = 0; r < 4; ++r) {
          const int m = m0 + w4 * 16 + rq * 4 + r;
          const int t = m & 63;
          attn_h[(size_t)(t * BB + b) * 512 + n] = acc[j][r] + bv;
        }
      }
    } else {                             // idle: match 8 iters x 2 barriers
      for (int q = 0; q < 16; ++q) __syncthreads();
    }
  }
  grid.sync();

  // ---------------- Phase A: scores + softmax + context ---------------------
  {
    float (*sc)[512]   = (float(*)[512])smem;            // [2][512]
    float (*ea1s)[512] = (float(*)[512])(smem + 4096);   // [2][512]
    float* v2s         = (float*)(smem + 12288);         // [512]
    float2* part       = (float2*)(smem + 4096);         // [2][4][256]
    float (*red)[8]    = (float(*)[8])(smem + 20480);    // [2][8]

    const int t0 = i * 2;
    const int wvA = tid >> 6, lane = tid & 63;
    const int hq = lane & 3, sl = lane >> 2;

    if (tid < 512) {
      ea1s[0][tid] = Ea1[(size_t)(b * TT + t0) * HH + tid];
      ea1s[1][tid] = Ea1[(size_t)(b * TT + t0 + 1) * HH + tid];
    } else {
      v2s[tid - 512] = 2.0f * v[tid - 512];
    }
    __syncthreads();

    // scores: 16 waves x 32 s, one pass
    const int s0 = wvA * 32 + sl;
    {
      const unsigned short* e2r0 = Ea2b + (size_t)(b * SS + s0) * HH;
      const unsigned short* e2r1 = e2r0 + (size_t)16 * HH;
      float acc[2][2] = {};
#define BFLO(u) __uint_as_float((u) << 16)
#define BFHI(u) __uint_as_float((u) & 0xffff0000u)
#define PAIR(E1a, E2a, Va, E1b, E2b, Vb, A)                                  \
      {                                                                      \
        const float x1 = fmaf(E1a, E2a, 1.0f), x2 = fmaf(E1b, E2b, 1.0f);    \
        const float rr = __builtin_amdgcn_rcpf(x1 * x2);                     \
        const float nn = fmaf(Va, x2, Vb * x1);                              \
        A = fmaf(nn, rr, A);                                                 \
      }
#pragma unroll 4
      for (int it = 0; it < 16; ++it) {
        const int h = it * 32 + hq * 8;
        const uint4 u0 = *(const uint4*)(e2r0 + h);
        const uint4 u1 = *(const uint4*)(e2r1 + h);
        const float4 va = *(const float4*)&v2s[h];
        const float4 vb = *(const float4*)&v2s[h + 4];
        float4 e1a[2], e1b[2];
        e1a[0] = *(const float4*)&ea1s[0][h]; e1b[0] = *(const float4*)&ea1s[0][h + 4];
        e1a[1] = *(const float4*)&ea1s[1][h]; e1b[1] = *(const float4*)&ea1s[1][h + 4];
#pragma unroll
        for (int ii = 0; ii < 2; ++ii) {
          PAIR(e1a[ii].x, BFLO(u0.x), va.x, e1a[ii].y, BFHI(u0.x), va.y, acc[ii][0]);
          PAIR(e1a[ii].z, BFLO(u0.y), va.z, e1a[ii].w, BFHI(u0.y), va.w, acc[ii][0]);
          PAIR(e1b[ii].x, BFLO(u0.z), vb.x, e1b[ii].y, BFHI(u0.z), vb.y, acc[ii][0]);
          PAIR(e1b[ii].z, BFLO(u0.w), vb.z, e1b[ii].w, BFHI(u0.w), vb.w, acc[ii][0]);
          PAIR(e1a[ii].x, BFLO(u1.x), va.x, e1a[ii].y, BFHI(u1.x), va.y, acc[ii][1]);
          PAIR(e1a[ii].z, BFLO(u1.y), va.z, e1a[ii].w, BFHI(u1.y), va.w, acc[ii][1]);
          PAIR(e1b[ii].x, BFLO(u1.z), vb.x, e1b[ii].y, BFHI(u1.z), vb.y, acc[ii][1]);
          PAIR(e1b[ii].z, BFLO(u1.w), vb.z, e1b[ii].w, BFHI(u1.w), vb.w, acc[ii][1]);
        }
      }
#undef PAIR
#undef BFLO
#undef BFHI
#pragma unroll
      for (int ii = 0; ii < 2; ++ii)
#pragma unroll
        for (int j = 0; j < 2; ++j) {
          acc[ii][j] += __shfl_xor(acc[ii][j], 1);
          acc[ii][j] += __shfl_xor(acc[ii][j], 2);
        }
      if (hq == 0) {
        sc[0][s0] = -acc[0][0]; sc[0][s0 + 16] = -acc[0][1];
        sc[1][s0] = -acc[1][0]; sc[1][s0 + 16] = -acc[1][1];
      }
    }
    __syncthreads();

    // softmax over s
    float x0 = 0.f, x1 = 0.f, e0 = 0.f, e1 = 0.f;
    if (tid < 512) {
      x0 = sc[0][tid]; x1 = sc[1][tid];
      float m0 = x0, m1 = x1;
#pragma unroll
      for (int off = 32; off; off >>= 1) {
        m0 = fmaxf(m0, __shfl_xor(m0, off));
        m1 = fmaxf(m1, __shfl_xor(m1, off));
      }
      if (lane == 0) { red[0][wvA] = m0; red[1][wvA] = m1; }
    }
    __syncthreads();
    {
      float m0 = red[0][0], m1 = red[1][0];
#pragma unroll
      for (int w2 = 1; w2 < 8; ++w2) { m0 = fmaxf(m0, red[0][w2]); m1 = fmaxf(m1, red[1][w2]); }
      __syncthreads();
      if (tid < 512) {
        e0 = __expf(x0 - m0); e1 = __expf(x1 - m1);
        float s0v = e0, s1v = e1;
#pragma unroll
        for (int off = 32; off; off >>= 1) {
          s0v += __shfl_xor(s0v, off);
          s1v += __shfl_xor(s1v, off);
        }
        if (lane == 0) { red[0][wvA] = s0v; red[1][wvA] = s1v; }
      }
    }
    __syncthreads();
    {
      float sum0 = 0.f, sum1 = 0.f;
#pragma unroll
      for (int w2 = 0; w2 < 8; ++w2) { sum0 += red[0][w2]; sum1 += red[1][w2]; }
      if (tid < 512) {
        const float a0 = e0 * __builtin_amdgcn_rcpf(sum0);
        const float a1 = e1 * __builtin_amdgcn_rcpf(sum1);
        align_out[(size_t)(t0 + 0) * BB * SS + b * SS + tid] = a0;
        align_out[(size_t)(t0 + 1) * BB * SS + b * SS + tid] = a1;
        sc[0][tid] = a0;
        sc[1][tid] = a1;
      }
    }
    __syncthreads();

    // context: q = s-quarter, hp = h-pair
    {
      const int q = tid >> 8, hp = tid & 255;
      const unsigned* ep = (const unsigned*)encpb + (size_t)b * SS * 256;
      float c00 = 0.f, c01 = 0.f, c10 = 0.f, c11 = 0.f;
#pragma unroll 8
      for (int s2 = q * 128; s2 < q * 128 + 128; ++s2) {
        const unsigned u = ep[s2 * 256 + hp];
        const float elo = __uint_as_float(u << 16);
        const float ehi = __uint_as_float(u & 0xffff0000u);
        const float av0 = sc[0][s2], av1 = sc[1][s2];
        c00 = fmaf(av0, elo, c00); c01 = fmaf(av0, ehi, c01);
        c10 = fmaf(av1, elo, c10); c11 = fmaf(av1, ehi, c11);
      }
      part[(0 * 4 + q) * 256 + hp] = make_float2(c00, c01);
      part[(1 * 4 + q) * 256 + hp] = make_float2(c10, c11);
    }
    __syncthreads();
    if (tid < 512) {
      const int t = tid >> 8, hp = tid & 255;
      float clo = 0.f, chi = 0.f;
#pragma unroll
      for (int q = 0; q < 4; ++q) {
        const float2 p = part[(t * 4 + q) * 256 + hp];
        clo += p.x; chi += p.y;
      }
      ((unsigned*)concatb)[(size_t)(b * TT + t0 + t) * 512 + hp] =
          (unsigned)f2bf(clo) | ((unsigned)f2bf(chi) << 16);
    }
  }
  grid.sync();

  // ---------------- Phase O: attn_h += c@Wo_top (split-K x8, fp32 atomics) --
  {
    const int sub = tid >> 8, st = tid & 255;
    if (sub < 2) {
      unsigned short (*As)[72] = (unsigned short(*)[72])(smem + sub * 18432);
      unsigned short (*Bs)[72] = (unsigned short(*)[72])(smem + sub * 18432 + 9216);
      const int ntile = (blk >> 3) & 7, kc = (blk >> 6) * 2 + sub;  // kc in [0,8)
      const int m0 = b * 64, n0 = ntile * 64;
      f32x4 acc[4] = {};
      gemm_tile<1024, 1024>(concatb, WoT, m0, n0, kc * 64, kc * 64 + 64, As, Bs, acc, st);
      const int w4 = st >> 6, lane = st & 63;
      const int col = lane & 15, rq = lane >> 4;
#pragma unroll
      for (int j = 0; j < 4; ++j) {
        const int n = n0 + j * 16 + col;
#pragma unroll
        for (int r = 0; r < 4; ++r) {
          const int m = m0 + w4 * 16 + rq * 4 + r;
          const int t = m & 63;
          unsafeAtomicAdd(&attn_h[(size_t)(t * BB + b) * 512 + n], acc[j][r]);
        }
      }
    } else {
      __syncthreads(); __syncthreads();   // match 1 iter x 2 barriers
    }
  }
}

// ===========================================================================
// LEGACY 4-kernel path (verified at 124 µs) — fallback if cooperative launch
// is unavailable. Identical math, original workspace layout.
// ===========================================================================
__global__ __launch_bounds__(256)
void k_prep(const float* __restrict__ enc, const float* __restrict__ cov,
            const float* __restrict__ wcov, const float* __restrict__ dec,
            const float* __restrict__ Wq, const float* __restrict__ Wc,
            const float* __restrict__ Wo,
            unsigned short* __restrict__ encpb, unsigned short* __restrict__ concatb,
            unsigned short* __restrict__ WqT, unsigned short* __restrict__ WcT,
            unsigned short* __restrict__ WoT) {
  __shared__ float tile[32][33];
  const int blk = blockIdx.x, tid = threadIdx.x;

  if (blk < 2048) {
    const int r = tid >> 7, c = (tid & 127) * 4;
    const int bs = blk * 2 + r;
    const int s = bs & 511, b = bs >> 9;
    const float4 ev = *(const float4*)(enc + (size_t)(s * BB + b) * HH + c);
    const float cv = cov[bs];
    const float4 wv = *(const float4*)(wcov + c);
    ushort4 o;
    o.x = f2bf(fast_tanh(ev.x + cv * wv.x));
    o.y = f2bf(fast_tanh(ev.y + cv * wv.y));
    o.z = f2bf(fast_tanh(ev.z + cv * wv.z));
    o.w = f2bf(fast_tanh(ev.w + cv * wv.w));
    *(ushort4*)(encpb + (size_t)bs * HH + c) = o;
  } else if (blk < 2304) {
    const int r = tid >> 7, c = (tid & 127) * 4;
    const int m = (blk - 2048) * 2 + r, t = m & 63, b = m >> 6;
    const float4 dv = *(const float4*)(dec + (size_t)(t * BB + b) * HH + c);
    ushort4 o;
    o.x = f2bf(dv.x); o.y = f2bf(dv.y); o.z = f2bf(dv.z); o.w = f2bf(dv.w);
    *(ushort4*)(concatb + (size_t)m * 1024 + 512 + c) = o;
  } else {
    int l = blk - 2304;
    const float* W; unsigned short* WT; int KT;
    if (l < 256)      { W = Wq; WT = WqT; KT = 512; }
    else if (l < 512) { W = Wc; WT = WcT; KT = 512; l -= 256; }
    else              { W = Wo; WT = WoT; KT = 1024; l -= 512; }
    const int n0 = (l & 15) * 32, k0 = (l >> 4) * 32;
    const int r = tid >> 3, c4 = (tid & 7) * 4;
    const float4 w = *(const float4*)(W + (size_t)(k0 + r) * 512 + n0 + c4);
    tile[r][c4 + 0] = w.x; tile[r][c4 + 1] = w.y;
    tile[r][c4 + 2] = w.z; tile[r][c4 + 3] = w.w;
    __syncthreads();
    unsigned short* o = WT + (size_t)(n0 + r) * KT + k0 + c4;
#pragma unroll
    for (int i = 0; i < 4; ++i) o[i] = f2bf(tile[c4 + i][r]);
  }
}

__global__ __launch_bounds__(256)
void k_gemm12(const unsigned short* __restrict__ concatb,
              const unsigned short* __restrict__ encpb,
              const unsigned short* __restrict__ WqT,
              const unsigned short* __restrict__ WcT,
              const unsigned short* __restrict__ WoT,
              const float* __restrict__ bq, const float* __restrict__ bo,
              float* __restrict__ Ea1, unsigned short* __restrict__ Ea2b,
              float* __restrict__ attn_h) {
  __shared__ unsigned short As[64][72];
  __shared__ unsigned short Bs[64][72];
  const int g = blockIdx.x, tid = threadIdx.x;
  const int w = tid >> 6, lane = tid & 63;
  const int col = lane & 15, rq = lane >> 4;

  if (g < 64) {
    const int m0 = (g >> 3) * 64, n0 = (g & 7) * 64;
    f32x4 acc[4] = {};
    gemm_tile<1024, 512>(concatb + 512, WqT, m0, n0, 0, 512, As, Bs, acc, tid);
#pragma unroll
    for (int j = 0; j < 4; ++j) {
      const int n = n0 + j * 16 + col;
      const float bv = bq[n];
#pragma unroll
      for (int r = 0; r < 4; ++r) {
        const int m = m0 + w * 16 + rq * 4 + r;
        float val = fminf(fmaxf(acc[j][r] + bv, -10.5f), 10.5f);
        Ea1[(size_t)m * 512 + n] = __expf(2.0f * val);
      }
    }
  } else if (g < 576) {
    const int u = g - 64;
    const int m0 = (u >> 3) * 64, n0 = (u & 7) * 64;
    f32x4 acc[4] = {};
    gemm_tile<512, 512>(encpb, WcT, m0, n0, 0, 512, As, Bs, acc, tid);
#pragma unroll
    for (int j = 0; j < 4; ++j) {
      const int n = n0 + j * 16 + col;
#pragma unroll
      for (int r = 0; r < 4; ++r) {
        const int m = m0 + w * 16 + rq * 4 + r;
        float val = fminf(fmaxf(acc[j][r], -10.5f), 10.5f);
        Ea2b[(size_t)m * 512 + n] = f2bf(__expf(2.0f * val));
      }
    }
  } else {
    const int u = g - 576;
    const int m0 = (u >> 3) * 64, n0 = (u & 7) * 64;
    f32x4 acc[4] = {};
    gemm_tile<1024, 1024>(concatb, WoT, m0, n0, 512, 1024, As, Bs, acc, tid);
#pragma unroll
    for (int j = 0; j < 4; ++j) {
      const int n = n0 + j * 16 + col;
      const float bv = bo[n];
#pragma unroll
      for (int r = 0; r < 4; ++r) {
        const int m = m0 + w * 16 + rq * 4 + r;
        const int bi = m >> 6, t = m & 63;
        attn_h[(size_t)(t * BB + bi) * 512 + n] = acc[j][r] + bv;
      }
    }
  }
}

__global__ __launch_bounds__(1024)
void k_attn(const float* __restrict__ Ea1, const unsigned short* __restrict__ Ea2b,
            const float* __restrict__ v, const unsigned short* __restrict__ encpb,
            float* __restrict__ align_out, unsigned short* __restrict__ concatb) {
  __shared__ __align__(16) char smem[20544];
  float (*sc)[512]   = (float(*)[512])smem;
  float (*ea1s)[512] = (float(*)[512])(smem + 4096);
  float* v2s         = (float*)(smem + 12288);
  float2* part       = (float2*)(smem + 4096);
  float (*red)[8]    = (float(*)[8])(smem + 20480);

  const int g = blockIdx.x, tid = threadIdx.x;
  const int b = g & 7, t0 = (g >> 3) * 2;
  const int wv = tid >> 6, lane = tid & 63;
  const int hq = lane & 3, sl = lane >> 2;

  if (tid < 512) {
    ea1s[0][tid] = Ea1[(size_t)(b * TT + t0) * HH + tid];
    ea1s[1][tid] = Ea1[(size_t)(b * TT + t0 + 1) * HH + tid];
  } else {
    v2s[tid - 512] = 2.0f * v[tid - 512];
  }
  __syncthreads();

  const int s0 = wv * 32 + sl;
  {
    const unsigned short* e2r0 = Ea2b + (size_t)(b * SS + s0) * HH;
    const unsigned short* e2r1 = e2r0 + (size_t)16 * HH;
    float acc[2][2] = {};
#define BFLO(u) __uint_as_float((u) << 16)
#define BFHI(u) __uint_as_float((u) & 0xffff0000u)
#define PAIR(E1a, E2a, Va, E1b, E2b, Vb, A)                                  \
    {                                                                        \
      const float x1 = fmaf(E1a, E2a, 1.0f), x2 = fmaf(E1b, E2b, 1.0f);      \
      const float rr = __builtin_amdgcn_rcpf(x1 * x2);                       \
      const float nn = fmaf(Va, x2, Vb * x1);                                \
      A = fmaf(nn, rr, A);                                                   \
    }
#pragma unroll 4
    for (int it = 0; it < 16; ++it) {
      const int h = it * 32 + hq * 8;
      const uint4 u0 = *(const uint4*)(e2r0 + h);
      const uint4 u1 = *(const uint4*)(e2r1 + h);
      const float4 va = *(const float4*)&v2s[h];
      const float4 vb = *(const float4*)&v2s[h + 4];
      float4 e1a[2], e1b[2];
      e1a[0] = *(const float4*)&ea1s[0][h]; e1b[0] = *(const float4*)&ea1s[0][h + 4];
      e1a[1] = *(const float4*)&ea1s[1][h]; e1b[1] = *(const float4*)&ea1s[1][h + 4];
#pragma unroll
      for (int i = 0; i < 2; ++i) {
        PAIR(e1a[i].x, BFLO(u0.x), va.x, e1a[i].y, BFHI(u0.x), va.y, acc[i][0]);
        PAIR(e1a[i].z, BFLO(u0.y), va.z, e1a[i].w, BFHI(u0.y), va.w, acc[i][0]);
        PAIR(e1b[i].x, BFLO(u0.z), vb.x, e1b[i].y, BFHI(u0.z), vb.y, acc[i][0]);
        PAIR(e1b[i].z, BFLO(u0.w), vb.z, e1b[i].w, BFHI(u0.w), vb.w, acc[i][0]);
        PAIR(e1a[i].x, BFLO(u1.x), va.x, e1a[i].y, BFHI(u1.x), va.y, acc[i][1]);
        PAIR(e1a[i].z, BFLO(u1.y), va.z, e1a[i].w, BFHI(u1.y), va.w, acc[i][1]);
        PAIR(e1b[i].x, BFLO(u1.z), vb.x, e1b[i].y, BFHI(u1.z), vb.y, acc[i][1]);
        PAIR(e1b[i].z, BFLO(u1.w), vb.z, e1b[i].w, BFHI(u1.w), vb.w, acc[i][1]);
      }
    }
#undef PAIR
#undef BFLO
#undef BFHI
#pragma unroll
    for (int i = 0; i < 2; ++i)
#pragma unroll
      for (int j = 0; j < 2; ++j) {
        acc[i][j] += __shfl_xor(acc[i][j], 1);
        acc[i][j] += __shfl_xor(acc[i][j], 2);
      }
    if (hq == 0) {
      sc[0][s0] = -acc[0][0]; sc[0][s0 + 16] = -acc[0][1];
      sc[1][s0] = -acc[1][0]; sc[1][s0 + 16] = -acc[1][1];
    }
  }
  __syncthreads();

  float x0 = 0.f, x1 = 0.f, e0 = 0.f, e1 = 0.f;
  if (tid < 512) {
    x0 = sc[0][tid]; x1 = sc[1][tid];
    float m0 = x0, m1 = x1;
#pragma unroll
    for (int off = 32; off; off >>= 1) {
      m0 = fmaxf(m0, __shfl_xor(m0, off));
      m1 = fmaxf(m1, __shfl_xor(m1, off));
    }
    if (lane == 0) { red[0][wv] = m0; red[1][wv] = m1; }
  }
  __syncthreads();
  {
    float m0 = red[0][0], m1 = red[1][0];
#pragma unroll
    for (int w2 = 1; w2 < 8; ++w2) { m0 = fmaxf(m0, red[0][w2]); m1 = fmaxf(m1, red[1][w2]); }
    __syncthreads();
    if (tid < 512) {
      e0 = __expf(x0 - m0); e1 = __expf(x1 - m1);
      float s0v = e0, s1v = e1;
#pragma unroll
      for (int off = 32; off; off >>= 1) {
        s0v += __shfl_xor(s0v, off);
        s1v += __shfl_xor(s1v, off);
      }
      if (lane == 0) { red[0][wv] = s0v; red[1][wv] = s1v; }
    }
  }
  __syncthreads();
  {
    float sum0 = 0.f, sum1 = 0.f;
#pragma unroll
    for (int w2 = 0; w2 < 8; ++w2) { sum0 += red[0][w2]; sum1 += red[1][w2]; }
    if (tid < 512) {
      const float a0 = e0 * __builtin_amdgcn_rcpf(sum0);
      const float a1 = e1 * __builtin_amdgcn_rcpf(sum1);
      align_out[(size_t)(t0 + 0) * BB * SS + b * SS + tid] = a0;
      align_out[(size_t)(t0 + 1) * BB * SS + b * SS + tid] = a1;
      sc[0][tid] = a0;
      sc[1][tid] = a1;
    }
  }
  __syncthreads();

  {
    const int q = tid >> 8, hp = tid & 255;
    const unsigned* ep = (const unsigned*)encpb + (size_t)b * SS * 256;
    float c00 = 0.f, c01 = 0.f, c10 = 0.f, c11 = 0.f;
#pragma unroll 8
    for (int s2 = q * 128; s2 < q * 128 + 128; ++s2) {
      const unsigned u = ep[s2 * 256 + hp];
      const float elo = __uint_as_float(u << 16);
      const float ehi = __uint_as_float(u & 0xffff0000u);
      const float av0 = sc[0][s2], av1 = sc[1][s2];
      c00 = fmaf(av0, elo, c00); c01 = fmaf(av0, ehi, c01);
      c10 = fmaf(av1, elo, c10); c11 = fmaf(av1, ehi, c11);
    }
    part[(0 * 4 + q) * 256 + hp] = make_float2(c00, c01);
    part[(1 * 4 + q) * 256 + hp] = make_float2(c10, c11);
  }
  __syncthreads();
  if (tid < 512) {
    const int t = tid >> 8, hp = tid & 255;
    float clo = 0.f, chi = 0.f;
#pragma unroll
    for (int q = 0; q < 4; ++q) {
      const float2 p = part[(t * 4 + q) * 256 + hp];
      clo += p.x; chi += p.y;
    }
    ((unsigned*)concatb)[(size_t)(b * TT + t0 + t) * 512 + hp] =
        (unsigned)f2bf(clo) | ((unsigned)f2bf(chi) << 16);
  }
}

__global__ __launch_bounds__(256)
void k_out(const unsigned short* __restrict__ A,
           const unsigned short* __restrict__ BT,
           float* __restrict__ C) {
  __shared__ unsigned short As[64][72];
  __shared__ unsigned short Bs[64][72];
  const int tid = threadIdx.x;
  const int w = tid >> 6, lane = tid & 63;
  const int tau = blockIdx.x >> 2, kc = blockIdx.x & 3;
  const int n0 = (tau & 7) * 64, m0 = (tau >> 3) * 64;

  f32x4 acc[4] = {};
  gemm_tile<1024, 1024>(A, BT, m0, n0, kc * 128, kc * 128 + 128, As, Bs, acc, tid);

  const int col = lane & 15, rq = lane >> 4;
#pragma unroll
  for (int j = 0; j < 4; ++j) {
    const int n = n0 + j * 16 + col;
#pragma unroll
    for (int r = 0; r < 4; ++r) {
      const int m = m0 + w * 16 + rq * 4 + r;
      const int bi = m >> 6, t = m & 63;
      unsafeAtomicAdd(&C[(size_t)(t * BB + bi) * 512 + n], acc[j][r]);
    }
  }
}

// ---------------------------------------------------------------------------
extern "C" void kernel_launch(void* const* d_in, const int* in_sizes, int n_in,
                              void* d_out, int out_size, void* d_ws, size_t ws_size,
                              hipStream_t stream) {
  const float* dec  = (const float*)d_in[0];
  const float* enc  = (const float*)d_in[1];
  const float* cov  = (const float*)d_in[2];
  const float* Wq   = (const float*)d_in[3];
  const float* bq   = (const float*)d_in[4];
  const float* Wc   = (const float*)d_in[5];
  const float* v    = (const float*)d_in[6];
  const float* Wo   = (const float*)d_in[7];
  const float* bo   = (const float*)d_in[8];
  const float* wcov = (const float*)d_in[9];

  float* out = (float*)d_out;
  float* attn_h    = out;                         // [T,B,H]
  float* align_out = out + (size_t)TT * BB * HH;  // [T,B,S]

  char* w = (char*)d_ws;
  const size_t MB = 1024 * 1024;

  // ---- fused layout ----
  unsigned short* encpb   = (unsigned short*)(w);            // 4 MB  [b][s][h]
  unsigned short* concatb = (unsigned short*)(w + 4 * MB);   // 1 MB  [b*64+t][1024]
  float*          Ea1     = (float*)(w + 5 * MB);            // 1 MB
  unsigned short* Ea2b    = (unsigned short*)(w + 6 * MB);   // 4 MB bf16
  unsigned short* wrepl   = (unsigned short*)(w + 16 * MB);  // 16 MB: 8 x 2MB replicas

  void* args[] = {(void*)&dec, (void*)&enc, (void*)&cov, (void*)&Wq, (void*)&bq,
                  (void*)&Wc, (void*)&v, (void*)&Wo, (void*)&bo, (void*)&wcov,
                  (void*)&encpb, (void*)&concatb, (void*)&Ea1, (void*)&Ea2b,
                  (void*)&wrepl, (void*)&attn_h, (void*)&align_out};
  hipError_t e = hipLaunchCooperativeKernel((const void*)k_fused, dim3(256),
                                            dim3(1024), args, 0, stream);
  if (e == hipSuccess) return;

  // ---- fallback: verified 4-kernel path (original layout) ----
  unsigned short* encpbL   = (unsigned short*)(w);
  unsigned short* WqT      = (unsigned short*)(w + 4 * MB);
  unsigned short* WcT      = (unsigned short*)(w + 4 * MB + 512 * 1024);
  unsigned short* WoT      = (unsigned short*)(w + 5 * MB);
  unsigned short* concatbL = (unsigned short*)(w + 6 * MB);
  float*          Ea1L     = (float*)(w + 7 * MB);
  unsigned short* Ea2bL    = (unsigned short*)(w + 8 * MB);

  k_prep<<<3328, 256, 0, stream>>>(enc, cov, wcov, dec, Wq, Wc, Wo,
                                   encpbL, concatbL, WqT, WcT, WoT);
  k_gemm12<<<640, 256, 0, stream>>>(concatbL, encpbL, WqT, WcT, WoT, bq, bo,
                                    Ea1L, Ea2bL, attn_h);
  k_attn<<<256, 1024, 0, stream>>>(Ea1L, Ea2bL, v, encpbL, align_out, concatbL);
  k_out<<<256, 256, 0, stream>>>(concatbL, WoT, attn_h);
}

// Round 2
// 145.536 us; speedup vs baseline: 1.6698x; 1.6698x over previous
//
#include <hip/hip_runtime.h>
#include <cstddef>

static constexpr int TT = 64;    // decoder steps
static constexpr int BB = 8;     // batch
static constexpr int SS = 512;   // source length
static constexpr int HH = 512;   // hidden

typedef __attribute__((ext_vector_type(8))) short bf16x8;
typedef __attribute__((ext_vector_type(4))) float f32x4;

__device__ __forceinline__ float fast_tanh(float x) {
  float e = __expf(2.0f * x);
  return 1.0f - 2.0f * __builtin_amdgcn_rcpf(e + 1.0f);
}
__device__ __forceinline__ unsigned short f2bf(float f) {
  unsigned u = __float_as_uint(f);
  return (unsigned short)((u + 0x7FFFu + ((u >> 16) & 1u)) >> 16);   // RNE
}
__device__ __forceinline__ float bflo(unsigned u) { return __uint_as_float(u << 16); }
__device__ __forceinline__ float bfhi(unsigned u) { return __uint_as_float(u & 0xffff0000u); }

// ---------------------------------------------------------------------------
// k_prep — all preprocessing, vectorized (float4/ushort4):
//  [0,2048):     encpb = bf16(tanh(enc + cov*wcov)), 2 bs-rows/block
//  [2048,2304):  dec pack -> concatb right half, 2 m-rows/block
//  [2304,3328):  weight transposes Wq,Wc,Wo (32x32 tiles -> WT[n][k] bf16)
// ---------------------------------------------------------------------------
__global__ __launch_bounds__(256)
void k_prep(const float* __restrict__ enc, const float* __restrict__ cov,
            const float* __restrict__ wcov, const float* __restrict__ dec,
            const float* __restrict__ Wq, const float* __restrict__ Wc,
            const float* __restrict__ Wo,
            unsigned short* __restrict__ encpb, unsigned short* __restrict__ concatb,
            unsigned short* __restrict__ WqT, unsigned short* __restrict__ WcT,
            unsigned short* __restrict__ WoT) {
  __shared__ float tile[32][33];
  const int blk = blockIdx.x, tid = threadIdx.x;

  if (blk < 2048) {
    const int r = tid >> 7, c = (tid & 127) * 4;
    const int bs = blk * 2 + r;
    const int s = bs & 511, b = bs >> 9;
    const float4 ev = *(const float4*)(enc + (size_t)(s * BB + b) * HH + c);
    const float cv = cov[bs];
    const float4 wv = *(const float4*)(wcov + c);
    ushort4 o;
    o.x = f2bf(fast_tanh(ev.x + cv * wv.x));
    o.y = f2bf(fast_tanh(ev.y + cv * wv.y));
    o.z = f2bf(fast_tanh(ev.z + cv * wv.z));
    o.w = f2bf(fast_tanh(ev.w + cv * wv.w));
    *(ushort4*)(encpb + (size_t)bs * HH + c) = o;
  } else if (blk < 2304) {
    const int r = tid >> 7, c = (tid & 127) * 4;
    const int m = (blk - 2048) * 2 + r, t = m & 63, b = m >> 6;   // m = b*64+t
    const float4 dv = *(const float4*)(dec + (size_t)(t * BB + b) * HH + c);
    ushort4 o;
    o.x = f2bf(dv.x); o.y = f2bf(dv.y); o.z = f2bf(dv.z); o.w = f2bf(dv.w);
    *(ushort4*)(concatb + (size_t)m * 1024 + 512 + c) = o;
  } else {
    int l = blk - 2304;
    const float* W; unsigned short* WT; int KT;
    if (l < 256)      { W = Wq; WT = WqT; KT = 512; }
    else if (l < 512) { W = Wc; WT = WcT; KT = 512; l -= 256; }
    else              { W = Wo; WT = WoT; KT = 1024; l -= 512; }
    const int n0 = (l & 15) * 32, k0 = (l >> 4) * 32;
    const int r = tid >> 3, c4 = (tid & 7) * 4;
    const float4 w = *(const float4*)(W + (size_t)(k0 + r) * 512 + n0 + c4);
    tile[r][c4 + 0] = w.x; tile[r][c4 + 1] = w.y;
    tile[r][c4 + 2] = w.z; tile[r][c4 + 3] = w.w;
    __syncthreads();
    unsigned short* o = WT + (size_t)(n0 + r) * KT + k0 + c4;
#pragma unroll
    for (int i = 0; i < 4; ++i) o[i] = f2bf(tile[c4 + i][r]);
  }
}

// ---------------------------------------------------------------------------
// 64x64 bf16 MFMA tile over K range. 256 thr / 4 waves.
// C/D layout: col=lane&15, row=(lane>>4)*4+reg (verified earlier).
// ---------------------------------------------------------------------------
template<int LDA, int LDB>
__device__ __forceinline__ void gemm_tile(const unsigned short* __restrict__ A,
                                          const unsigned short* __restrict__ BT,
                                          int m0, int n0, int kbeg, int kend,
                                          unsigned short (*As)[72],
                                          unsigned short (*Bs)[72],
                                          f32x4 acc[4]) {
  const int tid = threadIdx.x, w = tid >> 6, lane = tid & 63;
  const int lr = tid >> 2, lk = (tid & 3) * 16;
  const int fm = w * 16 + (lane & 15), fk = (lane >> 4) * 8;
  for (int k0 = kbeg; k0 < kend; k0 += 64) {
    const uint4* ga = (const uint4*)(A + (size_t)(m0 + lr) * LDA + k0 + lk);
    const uint4* gb = (const uint4*)(BT + (size_t)(n0 + lr) * LDB + k0 + lk);
    uint4 a0 = ga[0], a1 = ga[1], b0 = gb[0], b1 = gb[1];
    *(uint4*)&As[lr][lk] = a0;  *(uint4*)&As[lr][lk + 8] = a1;
    *(uint4*)&Bs[lr][lk] = b0;  *(uint4*)&Bs[lr][lk + 8] = b1;
    __syncthreads();
#pragma unroll
    for (int ks = 0; ks < 2; ++ks) {
      bf16x8 af = *(const bf16x8*)&As[fm][ks * 32 + fk];
#pragma unroll
      for (int j = 0; j < 4; ++j) {
        bf16x8 bf = *(const bf16x8*)&Bs[j * 16 + (lane & 15)][ks * 32 + fk];
        acc[j] = __builtin_amdgcn_mfma_f32_16x16x32_bf16(af, bf, acc[j], 0, 0, 0);
      }
    }
    __syncthreads();
  }
}

// ---------------------------------------------------------------------------
// k_gemm12 — three GEMM jobs in ONE launch (640 blocks):
//  g <  64: Ea1 (fp32) = exp(2*clamp(dec@Wq + bq, +-10.5))
//  g < 576: Ea2b (BF16) = exp(2*clamp(encp@Wc, +-10.5))   <- halves L2 stream
//  g < 640: attn_h base = dec@Wo_bot + bo (scattered [T,B,H]); k_attn adds c@Wo_top
// clamp +-10.5: pair-product (Ea1*Ea2+1)^2 <= 2.9e36 finite; tanh(10.5)=1-1.5e-9.
// ---------------------------------------------------------------------------
__global__ __launch_bounds__(256)
void k_gemm12(const unsigned short* __restrict__ concatb,
              const unsigned short* __restrict__ encpb,
              const unsigned short* __restrict__ WqT,
              const unsigned short* __restrict__ WcT,
              const unsigned short* __restrict__ WoT,
              const float* __restrict__ bq, const float* __restrict__ bo,
              float* __restrict__ Ea1, unsigned short* __restrict__ Ea2b,
              float* __restrict__ attn_h) {
  __shared__ unsigned short As[64][72];
  __shared__ unsigned short Bs[64][72];
  const int g = blockIdx.x, tid = threadIdx.x;
  const int w = tid >> 6, lane = tid & 63;
  const int col = lane & 15, rq = lane >> 4;

  if (g < 64) {                        // a1
    const int m0 = (g >> 3) * 64, n0 = (g & 7) * 64;
    f32x4 acc[4] = {};
    gemm_tile<1024, 512>(concatb + 512, WqT, m0, n0, 0, 512, As, Bs, acc);
#pragma unroll
    for (int j = 0; j < 4; ++j) {
      const int n = n0 + j * 16 + col;
      const float bv = bq[n];
#pragma unroll
      for (int r = 0; r < 4; ++r) {
        const int m = m0 + w * 16 + rq * 4 + r;
        float val = fminf(fmaxf(acc[j][r] + bv, -10.5f), 10.5f);
        Ea1[(size_t)m * 512 + n] = __expf(2.0f * val);
      }
    }
  } else if (g < 576) {                // a2 -> bf16
    const int u = g - 64;
    const int m0 = (u >> 3) * 64, n0 = (u & 7) * 64;
    f32x4 acc[4] = {};
    gemm_tile<512, 512>(encpb, WcT, m0, n0, 0, 512, As, Bs, acc);
#pragma unroll
    for (int j = 0; j < 4; ++j) {
      const int n = n0 + j * 16 + col;
#pragma unroll
      for (int r = 0; r < 4; ++r) {
        const int m = m0 + w * 16 + rq * 4 + r;
        float val = fminf(fmaxf(acc[j][r], -10.5f), 10.5f);
        Ea2b[(size_t)m * 512 + n] = f2bf(__expf(2.0f * val));
      }
    }
  } else {                             // attn_h base = dec@Wo_bot + bo
    const int u = g - 576;
    const int m0 = (u >> 3) * 64, n0 = (u & 7) * 64;
    f32x4 acc[4] = {};
    gemm_tile<1024, 1024>(concatb, WoT, m0, n0, 512, 1024, As, Bs, acc);
#pragma unroll
    for (int j = 0; j < 4; ++j) {
      const int n = n0 + j * 16 + col;
      const float bv = bo[n];
#pragma unroll
      for (int r = 0; r < 4; ++r) {
        const int m = m0 + w * 16 + rq * 4 + r;
        const int bi = m >> 6, t = m & 63;
        attn_h[(size_t)(t * BB + bi) * 512 + n] = acc[j][r] + bv;
      }
    }
  }
}

// ---------------------------------------------------------------------------
// k_attn — scores + softmax + context + FUSED output projection.
// 256 blocks (b, t-pair), 1024 thr.
// Scores (pair-rcp, bf16 Ea2): sc = -(sum_h 2 v_h/(Ea1*Ea2+1)).
// After context: c kept in f32 LDS; attn_h[t,b,n] += c[t,:]·WoT_top[n,:]
// (each (t,b,n) owned by exactly one thread -> plain read-add-write, no atomics).
// This removes the former k_out kernel + its boundary L2 flush entirely.
// ---------------------------------------------------------------------------
__global__ __launch_bounds__(1024)
void k_attn(const float* __restrict__ Ea1, const unsigned short* __restrict__ Ea2b,
            const float* __restrict__ v, const unsigned short* __restrict__ encpb,
            const unsigned short* __restrict__ WoT,
            float* __restrict__ align_out, float* __restrict__ attn_h) {
  __shared__ __align__(16) char smem[24640];
  float (*sc)[512]   = (float(*)[512])smem;            // [2][512] scores->align
  float (*ea1s)[512] = (float(*)[512])(smem + 4096);   // [2][512] (scores phase)
  float* v2s         = (float*)(smem + 12288);         // [512]    (scores phase)
  float2* part       = (float2*)(smem + 4096);         // [2][4][256] (ctx phase)
  float (*red)[8]    = (float(*)[8])(smem + 20480);    // [2][8]
  float* cs          = (float*)(smem + 20544);         // [2][512] f32 context

  const int g = blockIdx.x, tid = threadIdx.x;
  const int b = g & 7, t0 = (g >> 3) * 2;              // XCD-affine b
  const int wv = tid >> 6, lane = tid & 63;
  const int hq = lane & 3, sl = lane >> 2;

  if (tid < 512) {
    ea1s[0][tid] = Ea1[(size_t)(b * TT + t0) * HH + tid];
    ea1s[1][tid] = Ea1[(size_t)(b * TT + t0 + 1) * HH + tid];
  } else {
    v2s[tid - 512] = 2.0f * v[tid - 512];
  }
  __syncthreads();

  // ---- scores: 16 waves x 32 s, one pass; 32-h chunks (8 bf16/lane-load) ----
  const int s0 = wv * 32 + sl;                         // and s0+16
  {
    const unsigned short* e2r0 = Ea2b + (size_t)(b * SS + s0) * HH;
    const unsigned short* e2r1 = e2r0 + (size_t)16 * HH;
    float acc[2][2] = {};
#define PAIR(E1a, E2a, Va, E1b, E2b, Vb, A)                                  \
    {                                                                        \
      const float x1 = fmaf(E1a, E2a, 1.0f), x2 = fmaf(E1b, E2b, 1.0f);      \
      const float rr = __builtin_amdgcn_rcpf(x1 * x2);                       \
      const float nn = fmaf(Va, x2, Vb * x1);                                \
      A = fmaf(nn, rr, A);                                                   \
    }
#pragma unroll 4
    for (int it = 0; it < 16; ++it) {
      const int h = it * 32 + hq * 8;
      const uint4 u0 = *(const uint4*)(e2r0 + h);
      const uint4 u1 = *(const uint4*)(e2r1 + h);
      const float4 va = *(const float4*)&v2s[h];
      const float4 vb = *(const float4*)&v2s[h + 4];
      float4 e1a[2], e1b[2];
      e1a[0] = *(const float4*)&ea1s[0][h]; e1b[0] = *(const float4*)&ea1s[0][h + 4];
      e1a[1] = *(const float4*)&ea1s[1][h]; e1b[1] = *(const float4*)&ea1s[1][h + 4];
#pragma unroll
      for (int i = 0; i < 2; ++i) {
        PAIR(e1a[i].x, bflo(u0.x), va.x, e1a[i].y, bfhi(u0.x), va.y, acc[i][0]);
        PAIR(e1a[i].z, bflo(u0.y), va.z, e1a[i].w, bfhi(u0.y), va.w, acc[i][0]);
        PAIR(e1b[i].x, bflo(u0.z), vb.x, e1b[i].y, bfhi(u0.z), vb.y, acc[i][0]);
        PAIR(e1b[i].z, bflo(u0.w), vb.z, e1b[i].w, bfhi(u0.w), vb.w, acc[i][0]);
        PAIR(e1a[i].x, bflo(u1.x), va.x, e1a[i].y, bfhi(u1.x), va.y, acc[i][1]);
        PAIR(e1a[i].z, bflo(u1.y), va.z, e1a[i].w, bfhi(u1.y), va.w, acc[i][1]);
        PAIR(e1b[i].x, bflo(u1.z), vb.x, e1b[i].y, bfhi(u1.z), vb.y, acc[i][1]);
        PAIR(e1b[i].z, bflo(u1.w), vb.z, e1b[i].w, bfhi(u1.w), vb.w, acc[i][1]);
      }
    }
#undef PAIR
#pragma unroll
    for (int i = 0; i < 2; ++i)
#pragma unroll
      for (int j = 0; j < 2; ++j) {
        acc[i][j] += __shfl_xor(acc[i][j], 1);
        acc[i][j] += __shfl_xor(acc[i][j], 2);
      }
    if (hq == 0) {
      sc[0][s0] = -acc[0][0]; sc[0][s0 + 16] = -acc[0][1];
      sc[1][s0] = -acc[1][0]; sc[1][s0 + 16] = -acc[1][1];
    }
  }
  __syncthreads();

  // ---- softmax over s (threads < 512 own s=tid; all threads hit barriers) --
  float x0 = 0.f, x1 = 0.f, e0 = 0.f, e1 = 0.f;
  if (tid < 512) {
    x0 = sc[0][tid]; x1 = sc[1][tid];
    float m0 = x0, m1 = x1;
#pragma unroll
    for (int off = 32; off; off >>= 1) {
      m0 = fmaxf(m0, __shfl_xor(m0, off));
      m1 = fmaxf(m1, __shfl_xor(m1, off));
    }
    if (lane == 0) { red[0][wv] = m0; red[1][wv] = m1; }
  }
  __syncthreads();
  {
    float m0 = red[0][0], m1 = red[1][0];
#pragma unroll
    for (int w2 = 1; w2 < 8; ++w2) { m0 = fmaxf(m0, red[0][w2]); m1 = fmaxf(m1, red[1][w2]); }
    __syncthreads();
    if (tid < 512) {
      e0 = __expf(x0 - m0); e1 = __expf(x1 - m1);
      float s0v = e0, s1v = e1;
#pragma unroll
      for (int off = 32; off; off >>= 1) {
        s0v += __shfl_xor(s0v, off);
        s1v += __shfl_xor(s1v, off);
      }
      if (lane == 0) { red[0][wv] = s0v; red[1][wv] = s1v; }
    }
  }
  __syncthreads();
  {
    float sum0 = 0.f, sum1 = 0.f;
#pragma unroll
    for (int w2 = 0; w2 < 8; ++w2) { sum0 += red[0][w2]; sum1 += red[1][w2]; }
    if (tid < 512) {
      const float a0 = e0 * __builtin_amdgcn_rcpf(sum0);
      const float a1 = e1 * __builtin_amdgcn_rcpf(sum1);
      align_out[(size_t)(t0 + 0) * BB * SS + b * SS + tid] = a0;
      align_out[(size_t)(t0 + 1) * BB * SS + b * SS + tid] = a1;
      sc[0][tid] = a0;
      sc[1][tid] = a1;
    }
  }
  __syncthreads();

  // ---- context: q = s-quarter (tid>>8), hp = h-pair (tid&255) ----
  {
    const int q = tid >> 8, hp = tid & 255;
    const unsigned* ep = (const unsigned*)encpb + (size_t)b * SS * 256;
    float c00 = 0.f, c01 = 0.f, c10 = 0.f, c11 = 0.f;
#pragma unroll 8
    for (int s2 = q * 128; s2 < q * 128 + 128; ++s2) {
      const unsigned u = ep[s2 * 256 + hp];
      const float elo = bflo(u);
      const float ehi = bfhi(u);
      const float av0 = sc[0][s2], av1 = sc[1][s2];
      c00 = fmaf(av0, elo, c00); c01 = fmaf(av0, ehi, c01);
      c10 = fmaf(av1, elo, c10); c11 = fmaf(av1, ehi, c11);
    }
    part[(0 * 4 + q) * 256 + hp] = make_float2(c00, c01);
    part[(1 * 4 + q) * 256 + hp] = make_float2(c10, c11);
  }
  __syncthreads();
  if (tid < 512) {
    const int t = tid >> 8, hp = tid & 255;
    float clo = 0.f, chi = 0.f;
#pragma unroll
    for (int q = 0; q < 4; ++q) {
      const float2 p = part[(t * 4 + q) * 256 + hp];
      clo += p.x; chi += p.y;
    }
    cs[t * 512 + hp * 2]     = clo;
    cs[t * 512 + hp * 2 + 1] = chi;
  }
  __syncthreads();

  // ---- fused output projection: attn_h[t,b,n] += c[t,:]·WoT_top[n,:] ----
  {
    const int t = tid >> 9, n = tid & 511;
    const unsigned short* wr = WoT + (size_t)n * 1024;   // [n][k], top = k<512
    const float* ct = cs + t * 512;
    float acc = 0.f;
#pragma unroll 8
    for (int h = 0; h < 512; h += 8) {
      const uint4 u = *(const uint4*)(wr + h);
      const float4 c0 = *(const float4*)(ct + h);
      const float4 c1 = *(const float4*)(ct + h + 4);
      acc = fmaf(c0.x, bflo(u.x), acc); acc = fmaf(c0.y, bfhi(u.x), acc);
      acc = fmaf(c0.z, bflo(u.y), acc); acc = fmaf(c0.w, bfhi(u.y), acc);
      acc = fmaf(c1.x, bflo(u.z), acc); acc = fmaf(c1.y, bfhi(u.z), acc);
      acc = fmaf(c1.z, bflo(u.w), acc); acc = fmaf(c1.w, bfhi(u.w), acc);
    }
    const size_t oi = (size_t)((t0 + t) * BB + b) * 512 + n;
    attn_h[oi] += acc;   // base (dec@Wo_bot + bo) written by k_gemm12
  }
}

// ---------------------------------------------------------------------------
extern "C" void kernel_launch(void* const* d_in, const int* in_sizes, int n_in,
                              void* d_out, int out_size, void* d_ws, size_t ws_size,
                              hipStream_t stream) {
  const float* dec  = (const float*)d_in[0];
  const float* enc  = (const float*)d_in[1];
  const float* cov  = (const float*)d_in[2];
  const float* Wq   = (const float*)d_in[3];
  const float* bq   = (const float*)d_in[4];
  const float* Wc   = (const float*)d_in[5];
  const float* v    = (const float*)d_in[6];
  const float* Wo   = (const float*)d_in[7];
  const float* bo   = (const float*)d_in[8];
  const float* wcov = (const float*)d_in[9];

  float* out = (float*)d_out;
  float* attn_h    = out;                         // [T,B,H]
  float* align_out = out + (size_t)TT * BB * HH;  // [T,B,S]

  char* w = (char*)d_ws;
  const size_t MB = 1024 * 1024;
  unsigned short* encpb   = (unsigned short*)(w);                      // 4 MB
  unsigned short* WqT     = (unsigned short*)(w + 4 * MB);             // 0.5 MB
  unsigned short* WcT     = (unsigned short*)(w + 4 * MB + 512 * 1024);// 0.5 MB
  unsigned short* WoT     = (unsigned short*)(w + 5 * MB);             // 1 MB [n][1024]
  unsigned short* concatb = (unsigned short*)(w + 6 * MB);             // 1 MB [b*64+t][1024]
  float*          Ea1     = (float*)(w + 7 * MB);                      // 1 MB
  unsigned short* Ea2b    = (unsigned short*)(w + 8 * MB);             // 4 MB bf16

  k_prep<<<3328, 256, 0, stream>>>(enc, cov, wcov, dec, Wq, Wc, Wo,
                                   encpb, concatb, WqT, WcT, WoT);
  k_gemm12<<<640, 256, 0, stream>>>(concatb, encpb, WqT, WcT, WoT, bq, bo,
                                    Ea1, Ea2b, attn_h);
  k_attn<<<256, 1024, 0, stream>>>(Ea1, Ea2b, v, encpb, WoT, align_out, attn_h);
}